// Round 14
// baseline (50.615 us; speedup 1.0000x reference)
//
#include <hip/hip_runtime.h>

#define L_N    50000
#define K_DIM  512
#define GRID1  256             // one 1024-thread block per CU
#define NGRP   3125            // 50000 rows / 16 rows per wave-group
#define WS2    (33 * GRID1)    // input_x precompute slots at ws[8448..8511]
#define SB()   __builtin_amdgcn_sched_barrier(0)
// ws layout: float[33][256] partials + float[64] relu(input_x)

typedef __attribute__((ext_vector_type(8))) short bf16x8;
typedef __attribute__((ext_vector_type(4))) float f32x4;

// split 8 f32 into truncated-bf16 hi + bf16(residual) lo  (validated R2-R13: absmax 0.0)
__device__ __forceinline__ void split8(float4 a, float4 b, bf16x8& hi, bf16x8& lo) {
    float v[8] = {a.x, a.y, a.z, a.w, b.x, b.y, b.z, b.w};
    #pragma unroll
    for (int j = 0; j < 8; ++j) {
        unsigned u  = __float_as_uint(v[j]);
        unsigned hb = u & 0xFFFF0000u;
        float    lf = v[j] - __uint_as_float(hb);
        hi[j] = (short)(hb >> 16);
        lo[j] = (short)(__float_as_uint(lf) >> 16);
    }
}

__global__ __launch_bounds__(1024) void k_part(
    const float* __restrict__ other,   // [L][512]
    const float* __restrict__ W12,     // [32][512]
    const float* __restrict__ b12,     // [32]
    const float* __restrict__ Wa,      // [96]
    const float* __restrict__ inputs,  // [256]
    const float* __restrict__ act_idx, // [64]
    const float* __restrict__ W11,     // [64][320]
    const float* __restrict__ b11,     // [64]
    float* __restrict__ ws)            // [33][256] + [64]
{
    __shared__ short whi[16384];       // 32 KB
    __shared__ short wlo[16384];       // 32 KB
    __shared__ float sbuf[16][34];

    const int tid  = threadIdx.x;
    const int lane = tid & 63;
    const int wv   = tid >> 6;         // 0..15
    const int cl   = lane & 15;
    const int g    = lane >> 4;

    // ---- one-time per CU: W12 -> LDS pre-split (validated R4-R13) ----
    #pragma unroll
    for (int c2 = 0; c2 < 2; ++c2) {
        const int u  = tid + c2 * 1024;
        const int ch = u >> 6, r = u & 63;
        const float* wp = W12 + (size_t)ch * K_DIM + (r >> 2) * 32 + (r & 3) * 4;
        const float4 f0 = *(const float4*)wp;
        const float4 f1 = *(const float4*)(wp + 16);
        bf16x8 h8, l8; split8(f0, f1, h8, l8);
        const int p = (r * 32 + (ch ^ (r & 31))) * 8;
        *(bf16x8*)&whi[p] = h8;
        *(bf16x8*)&wlo[p] = l8;
    }
    __syncthreads();

    float rps = 0.f, rm0 = 0.f, rm1 = 0.f;
    const int wid = wv * GRID1 + blockIdx.x;     // transposed map (R13)

    if (wid < NGRP) {
        const float b0 = b12[cl],     b1 = b12[16 + cl];
        const float w0 = Wa[64 + cl], w1 = Wa[80 + cl];

        const float* xp = other + (size_t)(wid * 16 + cl) * K_DIM + (g << 2);

        float4 a0, a1, a2, a3, b0v, b1v, b2v, b3v, c0v, c1v, c2v, c3v, d0v, d1v, d2v, d3v;

        #define GLD(dst, OFF)                                                  \
            asm volatile("global_load_dwordx4 %0, %1, off offset:" OFF        \
                         : "=v"(dst) : "v"(xp) : "memory")
        #define GLDQ(x0,x1,x2,x3, O0,O1,O2,O3) do {                            \
            GLD(x0, O0); GLD(x1, O1); GLD(x2, O2); GLD(x3, O3);                \
        } while (0)
        #define VMW(N) do {                                                    \
            asm volatile("s_waitcnt vmcnt(" #N ")" ::: "memory");              \
            __builtin_amdgcn_sched_barrier(0);                                 \
        } while (0)

        f32x4 acc0 = {0.f,0.f,0.f,0.f}, acc1 = {0.f,0.f,0.f,0.f};

        #define CONSH(xlo, xhi, KC) do {                                       \
            bf16x8 ah, al; split8(xlo, xhi, ah, al);                           \
            const int r_  = (KC) * 4 + g;                                      \
            const int u0_ = (r_ * 32 + (cl ^ (r_ & 31))) * 8;                  \
            const bf16x8 bh0 = *(const bf16x8*)&whi[u0_];                      \
            const bf16x8 bl0 = *(const bf16x8*)&wlo[u0_];                      \
            const bf16x8 bh1 = *(const bf16x8*)&whi[u0_ ^ 128];                \
            const bf16x8 bl1 = *(const bf16x8*)&wlo[u0_ ^ 128];                \
            acc0 = __builtin_amdgcn_mfma_f32_16x16x32_bf16(ah, bh0, acc0, 0, 0, 0); \
            acc0 = __builtin_amdgcn_mfma_f32_16x16x32_bf16(al, bh0, acc0, 0, 0, 0); \
            acc0 = __builtin_amdgcn_mfma_f32_16x16x32_bf16(ah, bl0, acc0, 0, 0, 0); \
            acc1 = __builtin_amdgcn_mfma_f32_16x16x32_bf16(ah, bh1, acc1, 0, 0, 0); \
            acc1 = __builtin_amdgcn_mfma_f32_16x16x32_bf16(al, bh1, acc1, 0, 0, 0); \
            acc1 = __builtin_amdgcn_mfma_f32_16x16x32_bf16(ah, bl1, acc1, 0, 0, 0); \
        } while (0)
        #define CONSQ(x0,x1,x2,x3, QQ) do {                                    \
            CONSH(x0, x1, 2*(QQ));                                             \
            CONSH(x2, x3, 2*(QQ)+1);                                           \
        } while (0)

        GLDQ(a0,a1,a2,a3,     "0",    "64",   "128",  "192");
        GLDQ(b0v,b1v,b2v,b3v, "256",  "320",  "384",  "448");
        GLDQ(c0v,c1v,c2v,c3v, "512",  "576",  "640",  "704");
        GLDQ(d0v,d1v,d2v,d3v, "768",  "832",  "896",  "960");
        VMW(12); CONSQ(a0,a1,a2,a3, 0);  GLDQ(a0,a1,a2,a3, "1024","1088","1152","1216");
        VMW(12); CONSQ(b0v,b1v,b2v,b3v, 1); GLDQ(b0v,b1v,b2v,b3v, "1280","1344","1408","1472");
        VMW(12); CONSQ(c0v,c1v,c2v,c3v, 2); GLDQ(c0v,c1v,c2v,c3v, "1536","1600","1664","1728");
        VMW(12); CONSQ(d0v,d1v,d2v,d3v, 3); GLDQ(d0v,d1v,d2v,d3v, "1792","1856","1920","1984");
        VMW(12); CONSQ(a0,a1,a2,a3, 4);
        VMW(8);  CONSQ(b0v,b1v,b2v,b3v, 5);
        VMW(4);  CONSQ(c0v,c1v,c2v,c3v, 6);
        VMW(0);  CONSQ(d0v,d1v,d2v,d3v, 7);

        float e0[4], e1[4], s4[4];
        #pragma unroll
        for (int i = 0; i < 4; ++i) {
            e0[i] = acc0[i] + b0;
            e1[i] = acc1[i] + b1;
            s4[i] = fmaxf(e0[i], 0.f) * w0 + fmaxf(e1[i], 0.f) * w1;
        }
        #pragma unroll
        for (int d = 1; d < 16; d <<= 1) {
            #pragma unroll
            for (int i = 0; i < 4; ++i) s4[i] += __shfl_xor(s4[i], d);
        }
        #pragma unroll
        for (int i = 0; i < 4; ++i) {
            const float p = __expf(s4[i]);
            rps += p;
            rm0 = fmaf(p, e0[i], rm0);
            rm1 = fmaf(p, e1[i], rm1);
        }
    } else if (blockIdx.x == 0 && wv == 13) {
        // idle wave repurposed: input_x precompute, bit-exact k_final order.
        // lane = output h; 4 accs of 80 sequential fmas, combined ((a0+a1)+(a2+a3)).
        const float* wrow = W11 + lane * 320;
        float aq[4];
        #pragma unroll
        for (int qq = 0; qq < 4; ++qq) {
            float s = 0.f;
            #pragma unroll
            for (int i = 0; i < 20; ++i) {
                const float4 f = *(const float4*)(wrow + qq * 80 + i * 4);
                const int k = qq * 80 + i * 4;
                const float x0 = (k     < 256) ? inputs[k]     : act_idx[k - 256];
                const float x1 = (k + 1 < 256) ? inputs[k + 1] : act_idx[k - 255];
                const float x2 = (k + 2 < 256) ? inputs[k + 2] : act_idx[k - 254];
                const float x3 = (k + 3 < 256) ? inputs[k + 3] : act_idx[k - 253];
                s = fmaf(f.x, x0, s);
                s = fmaf(f.y, x1, s);
                s = fmaf(f.z, x2, s);
                s = fmaf(f.w, x3, s);
            }
            aq[qq] = s;
        }
        const float ix = ((aq[0] + aq[1]) + (aq[2] + aq[3])) + b11[lane];
        ws[WS2 + lane] = fmaxf(ix, 0.f);
    }

    // ---- block reduce: 33 plain stores (channel-major) ----
    rps += __shfl_xor(rps, 16); rps += __shfl_xor(rps, 32);
    rm0 += __shfl_xor(rm0, 16); rm0 += __shfl_xor(rm0, 32);
    rm1 += __shfl_xor(rm1, 16); rm1 += __shfl_xor(rm1, 32);
    if (lane == 0)  sbuf[wv][0] = rps;
    if (lane < 16) { sbuf[wv][1 + cl] = rm0; sbuf[wv][17 + cl] = rm1; }
    __syncthreads();
    if (wv == 0 && lane < 33) {
        float v = 0.f;
        #pragma unroll
        for (int s = 0; s < 16; ++s) v += sbuf[s][lane];
        ws[lane * GRID1 + blockIdx.x] = v;
    }
}

__global__ __launch_bounds__(256) void k_final(
    const float* __restrict__ ws,       // [33][256] + [64]
    const float* __restrict__ Wao, const float* __restrict__ bao,
    const float* __restrict__ W2,  const float* __restrict__ b2,
    const float* __restrict__ W3,  const float* __restrict__ b3,
    float* __restrict__ out)            // [33]: r, samples[32]
{
    __shared__ float wsl[33];
    __shared__ float rm[32], z[32], xcat[96], h64[64];
    __shared__ int   amax;

    const int t = threadIdx.x, hh = t >> 2, q = t & 3;

    // parallel vectorized cross-block reduction: 132 threads, 64 floats each
    if (t < 132) {
        const int c = t >> 2, seg = t & 3;
        const float4* p = (const float4*)(ws + c * GRID1 + seg * 64);
        float v = 0.f;
        #pragma unroll
        for (int i = 0; i < 16; ++i) { const float4 f = p[i]; v += f.x + f.y + f.z + f.w; }
        v += __shfl_xor(v, 1);
        v += __shfl_xor(v, 2);
        if (seg == 0) wsl[c] = v;
    }
    const float xw = (t < 64) ? ws[WS2 + t] : 0.f;   // precomputed relu(input_x)
    __syncthreads();

    if (t < 32) rm[t] = fmaxf(wsl[1 + t] / wsl[0], 0.f);
    __syncthreads();

    // attn_out logits: 8 threads per output, 4 k each
    {
        const int o = t >> 3, kb = (t & 7) * 4;
        float zz = 0.f;
        #pragma unroll
        for (int j = 0; j < 4; ++j) zz = fmaf(Wao[o * 32 + kb + j], rm[kb + j], zz);
        zz += __shfl_xor(zz, 1);
        zz += __shfl_xor(zz, 2);
        zz += __shfl_xor(zz, 4);
        if ((t & 7) == 0) z[o] = zz + bao[o];
    }
    __syncthreads();

    // parallel argmax, first-max tiebreak (matches jnp.argmax)
    if (t < 32) {
        float bv = z[t]; int bi = t;
        #pragma unroll
        for (int d = 1; d < 32; d <<= 1) {
            const float ov = __shfl_xor(bv, d);
            const int   oi = __shfl_xor(bi, d);
            if (ov > bv || (ov == bv && oi < bi)) { bv = ov; bi = oi; }
        }
        if (t == 0) amax = bi;
    }
    if (t < 64) xcat[t] = xw;
    __syncthreads();
    if (t < 32) xcat[64 + t] = (t == amax) ? 1.f : 0.f;  // one_hot_st == samples
    __syncthreads();

    float dp = 0.f;
    for (int i = 0; i < 24; ++i) {
        const int k = q * 24 + i;
        dp = fmaf(W2[hh * 96 + k], xcat[k], dp);
    }
    dp += __shfl_xor(dp, 1);
    dp += __shfl_xor(dp, 2);
    if (q == 0) h64[hh] = fmaxf(dp + b2[hh], 0.f);
    __syncthreads();

    if (t < 64) {
        float r = W3[t] * h64[t];
        #pragma unroll
        for (int d = 1; d < 64; d <<= 1) r += __shfl_xor(r, d);
        if (t == 0) out[0] = r + b3[0];
    }
    if (t < 32) out[1 + t] = (t == amax) ? 1.f : 0.f;
}

extern "C" void kernel_launch(void* const* d_in, const int* in_sizes, int n_in,
                              void* d_out, int out_size, void* d_ws, size_t ws_size,
                              hipStream_t stream) {
    const float* inputs  = (const float*)d_in[0];
    const float* act_idx = (const float*)d_in[1];
    const float* other   = (const float*)d_in[2];
    const float* W11     = (const float*)d_in[3];
    const float* b11     = (const float*)d_in[4];
    const float* W12     = (const float*)d_in[5];
    const float* b12     = (const float*)d_in[6];
    const float* Wa      = (const float*)d_in[7];
    // d_in[8] = ba : unused (softmax shift-invariant)
    const float* Wao     = (const float*)d_in[9];
    const float* bao     = (const float*)d_in[10];
    const float* W2      = (const float*)d_in[11];
    const float* b2      = (const float*)d_in[12];
    const float* W3      = (const float*)d_in[13];
    const float* b3      = (const float*)d_in[14];
    float* ws = (float*)d_ws;

    // MEASUREMENT ROUND: k_part dispatched TWICE (idempotent plain stores;
    // same-stream ordering). dur - 33.1 ≈ kp_warm + launch - kf_savings.
    k_part<<<GRID1, 1024, 0, stream>>>(other, W12, b12, Wa,
                                       inputs, act_idx, W11, b11, ws);
    k_part<<<GRID1, 1024, 0, stream>>>(other, W12, b12, Wa,
                                       inputs, act_idx, W11, b11, ws);
    k_final<<<1, 256, 0, stream>>>(ws, Wao, bao, W2, b2, W3, b3, (float*)d_out);
}

// Round 15
// 29.584 us; speedup vs baseline: 1.7109x; 1.7109x over previous
//
#include <hip/hip_runtime.h>

#define L_N    50000
#define K_DIM  512
#define GRID1  256             // one 1024-thread block per CU
#define NGRP   3125            // 50000 rows / 16 rows per wave-group
#define WS2    (33 * GRID1)    // relu(input_x) slots at ws[8448..8511]
#define SB()   __builtin_amdgcn_sched_barrier(0)
// ws layout: float[33][256] partials + float[64] relu(input_x)

typedef __attribute__((ext_vector_type(8))) short bf16x8;
typedef __attribute__((ext_vector_type(4))) float f32x4;

// split 8 f32 into truncated-bf16 hi + bf16(residual) lo  (validated R2-R14: absmax 0.0)
__device__ __forceinline__ void split8(float4 a, float4 b, bf16x8& hi, bf16x8& lo) {
    float v[8] = {a.x, a.y, a.z, a.w, b.x, b.y, b.z, b.w};
    #pragma unroll
    for (int j = 0; j < 8; ++j) {
        unsigned u  = __float_as_uint(v[j]);
        unsigned hb = u & 0xFFFF0000u;
        float    lf = v[j] - __uint_as_float(hb);
        hi[j] = (short)(hb >> 16);
        lo[j] = (short)(__float_as_uint(lf) >> 16);
    }
}

__global__ __launch_bounds__(1024) void k_part(
    const float* __restrict__ other,   // [L][512]
    const float* __restrict__ W12,     // [32][512]
    const float* __restrict__ b12,     // [32]
    const float* __restrict__ Wa,      // [96]
    const float* __restrict__ inputs,  // [256]
    const float* __restrict__ act_idx, // [64]
    const float* __restrict__ W11,     // [64][320]
    const float* __restrict__ b11,     // [64]
    float* __restrict__ ws)            // [33][256] + [64]
{
    __shared__ short whi[16384];       // 32 KB
    __shared__ short wlo[16384];       // 32 KB
    __shared__ float sbuf[16][34];

    const int tid  = threadIdx.x;
    const int lane = tid & 63;
    const int wv   = tid >> 6;         // 0..15
    const int cl   = lane & 15;
    const int g    = lane >> 4;

    const int wid  = wv * GRID1 + blockIdx.x;    // transposed map (R13)
    const bool act = (wid < NGRP);
    const float* xp = other + (size_t)((act ? wid : 0) * 16 + cl) * K_DIM + (g << 2);

    float4 a0, a1, a2, a3, b0v, b1v, b2v, b3v, c0v, c1v, c2v, c3v, d0v, d1v, d2v, d3v;

    #define GLD(dst, OFF)                                                  \
        asm volatile("global_load_dwordx4 %0, %1, off offset:" OFF        \
                     : "=v"(dst) : "v"(xp) : "memory")
    #define GLDQ(x0,x1,x2,x3, O0,O1,O2,O3) do {                            \
        GLD(x0, O0); GLD(x1, O1); GLD(x2, O2); GLD(x3, O3);                \
    } while (0)
    #define VMW(N) do {                                                    \
        asm volatile("s_waitcnt vmcnt(" #N ")" ::: "memory");              \
        __builtin_amdgcn_sched_barrier(0);                                 \
    } while (0)

    // ---- head start: quarters 0-1 fly under the W12 prologue; the barrier's
    // implicit vmcnt(0) drain retires them exactly when the prologue ends ----
    GLDQ(a0,a1,a2,a3,     "0",   "64",  "128",  "192");
    GLDQ(b0v,b1v,b2v,b3v, "256", "320", "384",  "448");
    SB();

    // ---- one-time per CU: W12 -> LDS pre-split (validated R4-R14) ----
    #pragma unroll
    for (int c2 = 0; c2 < 2; ++c2) {
        const int u  = tid + c2 * 1024;
        const int ch = u >> 6, r = u & 63;
        const float* wp = W12 + (size_t)ch * K_DIM + (r >> 2) * 32 + (r & 3) * 4;
        const float4 f0 = *(const float4*)wp;
        const float4 f1 = *(const float4*)(wp + 16);
        bf16x8 h8, l8; split8(f0, f1, h8, l8);
        const int p = (r * 32 + (ch ^ (r & 31))) * 8;
        *(bf16x8*)&whi[p] = h8;
        *(bf16x8*)&wlo[p] = l8;
    }
    __syncthreads();

    float rps = 0.f, rm0 = 0.f, rm1 = 0.f;

    if (act) {
        const float b0 = b12[cl],     b1 = b12[16 + cl];
        const float w0 = Wa[64 + cl], w1 = Wa[80 + cl];

        f32x4 acc0 = {0.f,0.f,0.f,0.f}, acc1 = {0.f,0.f,0.f,0.f};

        #define CONSH(xlo, xhi, KC) do {                                       \
            bf16x8 ah, al; split8(xlo, xhi, ah, al);                           \
            const int r_  = (KC) * 4 + g;                                      \
            const int u0_ = (r_ * 32 + (cl ^ (r_ & 31))) * 8;                  \
            const bf16x8 bh0 = *(const bf16x8*)&whi[u0_];                      \
            const bf16x8 bl0 = *(const bf16x8*)&wlo[u0_];                      \
            const bf16x8 bh1 = *(const bf16x8*)&whi[u0_ ^ 128];                \
            const bf16x8 bl1 = *(const bf16x8*)&wlo[u0_ ^ 128];                \
            acc0 = __builtin_amdgcn_mfma_f32_16x16x32_bf16(ah, bh0, acc0, 0, 0, 0); \
            acc0 = __builtin_amdgcn_mfma_f32_16x16x32_bf16(al, bh0, acc0, 0, 0, 0); \
            acc0 = __builtin_amdgcn_mfma_f32_16x16x32_bf16(ah, bl0, acc0, 0, 0, 0); \
            acc1 = __builtin_amdgcn_mfma_f32_16x16x32_bf16(ah, bh1, acc1, 0, 0, 0); \
            acc1 = __builtin_amdgcn_mfma_f32_16x16x32_bf16(al, bh1, acc1, 0, 0, 0); \
            acc1 = __builtin_amdgcn_mfma_f32_16x16x32_bf16(ah, bl1, acc1, 0, 0, 0); \
        } while (0)
        #define CONSQ(x0,x1,x2,x3, QQ) do {                                    \
            CONSH(x0, x1, 2*(QQ));                                             \
            CONSH(x2, x3, 2*(QQ)+1);                                           \
        } while (0)

        // quarters 0-1 already resident; refill and roll (validated R11-R14)
        GLDQ(c0v,c1v,c2v,c3v, "512",  "576",  "640",  "704");
        GLDQ(d0v,d1v,d2v,d3v, "768",  "832",  "896",  "960");
        CONSQ(a0,a1,a2,a3, 0);      GLDQ(a0,a1,a2,a3, "1024","1088","1152","1216");
        CONSQ(b0v,b1v,b2v,b3v, 1);  GLDQ(b0v,b1v,b2v,b3v, "1280","1344","1408","1472");
        VMW(12); CONSQ(c0v,c1v,c2v,c3v, 2); GLDQ(c0v,c1v,c2v,c3v, "1536","1600","1664","1728");
        VMW(12); CONSQ(d0v,d1v,d2v,d3v, 3); GLDQ(d0v,d1v,d2v,d3v, "1792","1856","1920","1984");
        VMW(12); CONSQ(a0,a1,a2,a3, 4);
        VMW(8);  CONSQ(b0v,b1v,b2v,b3v, 5);
        VMW(4);  CONSQ(c0v,c1v,c2v,c3v, 6);
        VMW(0);  CONSQ(d0v,d1v,d2v,d3v, 7);

        float e0[4], e1[4], s4[4];
        #pragma unroll
        for (int i = 0; i < 4; ++i) {
            e0[i] = acc0[i] + b0;
            e1[i] = acc1[i] + b1;
            s4[i] = fmaxf(e0[i], 0.f) * w0 + fmaxf(e1[i], 0.f) * w1;
        }
        #pragma unroll
        for (int d = 1; d < 16; d <<= 1) {
            #pragma unroll
            for (int i = 0; i < 4; ++i) s4[i] += __shfl_xor(s4[i], d);
        }
        #pragma unroll
        for (int i = 0; i < 4; ++i) {
            const float p = __expf(s4[i]);
            rps += p;
            rm0 = fmaf(p, e0[i], rm0);
            rm1 = fmaf(p, e1[i], rm1);
        }
    } else if (blockIdx.x == 0 && wv == 13) {
        // idle wave: relu(input_x), bit-exact k_final order (validated R14)
        const float* wrow = W11 + lane * 320;
        float aq[4];
        #pragma unroll
        for (int qq = 0; qq < 4; ++qq) {
            float s = 0.f;
            #pragma unroll
            for (int i = 0; i < 20; ++i) {
                const float4 f = *(const float4*)(wrow + qq * 80 + i * 4);
                const int k = qq * 80 + i * 4;
                const float x0 = (k     < 256) ? inputs[k]     : act_idx[k - 256];
                const float x1 = (k + 1 < 256) ? inputs[k + 1] : act_idx[k - 255];
                const float x2 = (k + 2 < 256) ? inputs[k + 2] : act_idx[k - 254];
                const float x3 = (k + 3 < 256) ? inputs[k + 3] : act_idx[k - 253];
                s = fmaf(f.x, x0, s);
                s = fmaf(f.y, x1, s);
                s = fmaf(f.z, x2, s);
                s = fmaf(f.w, x3, s);
            }
            aq[qq] = s;
        }
        const float ix = ((aq[0] + aq[1]) + (aq[2] + aq[3])) + b11[lane];
        ws[WS2 + lane] = fmaxf(ix, 0.f);
    }

    // ---- block reduce: 33 plain stores (channel-major) ----
    rps += __shfl_xor(rps, 16); rps += __shfl_xor(rps, 32);
    rm0 += __shfl_xor(rm0, 16); rm0 += __shfl_xor(rm0, 32);
    rm1 += __shfl_xor(rm1, 16); rm1 += __shfl_xor(rm1, 32);
    if (lane == 0)  sbuf[wv][0] = rps;
    if (lane < 16) { sbuf[wv][1 + cl] = rm0; sbuf[wv][17 + cl] = rm1; }
    __syncthreads();
    if (wv == 0 && lane < 33) {
        float v = 0.f;
        #pragma unroll
        for (int s = 0; s < 16; ++s) v += sbuf[s][lane];
        ws[lane * GRID1 + blockIdx.x] = v;
    }
}

__global__ __launch_bounds__(256) void k_final(
    const float* __restrict__ ws,       // [33][256] + [64]
    const float* __restrict__ Wao, const float* __restrict__ bao,
    const float* __restrict__ W2,  const float* __restrict__ b2,
    const float* __restrict__ W3,  const float* __restrict__ b3,
    float* __restrict__ out)            // [33]: r, samples[32]
{
    __shared__ float wsl[33];
    __shared__ float rm[32], z[32], xcat[96], h64[64];
    __shared__ int   amax;

    const int t = threadIdx.x, hh = t >> 2, q = t & 3;

    // ======== ENTRY PREFETCH: every global load issued up front, ONE latency ========
    float4 wsv[16];
    {
        const int c = (t < 132) ? (t >> 2) : 0, seg = (t < 132) ? (t & 3) : 0;
        const float4* p = (const float4*)(ws + c * GRID1 + seg * 64);
        #pragma unroll
        for (int i = 0; i < 16; ++i) wsv[i] = p[i];
    }
    const float  xw   = ws[WS2 + (t & 63)];               // relu(input_x)
    const float4 waov = *(const float4*)(Wao + (t >> 3) * 32 + (t & 7) * 4);
    const float  baov = bao[t >> 3];
    float4 w2v[6];
    #pragma unroll
    for (int j = 0; j < 6; ++j)
        w2v[j] = *(const float4*)(W2 + hh * 96 + q * 24 + j * 4);
    const float w3v = W3[t & 63];
    const float b2v = b2[hh];
    const float b3v = b3[0];

    // ======== register/LDS-only chain from here ========
    if (t < 132) {
        float v = 0.f;
        #pragma unroll
        for (int i = 0; i < 16; ++i) { const float4 f = wsv[i]; v += f.x + f.y + f.z + f.w; }
        v += __shfl_xor(v, 1);
        v += __shfl_xor(v, 2);
        if ((t & 3) == 0) wsl[t >> 2] = v;
    }
    __syncthreads();

    if (t < 32) rm[t] = fmaxf(wsl[1 + t] / wsl[0], 0.f);
    if (t < 64) xcat[t] = xw;                             // relu(one_hot) == one_hot later
    __syncthreads();

    // attn_out logits: 8 threads per output, 4 k each (prefetched Wao)
    {
        float zz = 0.f;
        const int kb = (t & 7) * 4;
        zz = fmaf(waov.x, rm[kb],     zz);
        zz = fmaf(waov.y, rm[kb + 1], zz);
        zz = fmaf(waov.z, rm[kb + 2], zz);
        zz = fmaf(waov.w, rm[kb + 3], zz);
        zz += __shfl_xor(zz, 1);
        zz += __shfl_xor(zz, 2);
        zz += __shfl_xor(zz, 4);
        if ((t & 7) == 0) z[t >> 3] = zz + baov;
    }
    __syncthreads();

    // parallel argmax, first-max tiebreak (matches jnp.argmax)
    if (t < 32) {
        float bv = z[t]; int bi = t;
        #pragma unroll
        for (int d = 1; d < 32; d <<= 1) {
            const float ov = __shfl_xor(bv, d);
            const int   oi = __shfl_xor(bi, d);
            if (ov > bv || (ov == bv && oi < bi)) { bv = ov; bi = oi; }
        }
        if (t == 0) amax = bi;
    }
    __syncthreads();
    if (t < 32) xcat[64 + t] = (t == amax) ? 1.f : 0.f;   // one_hot_st == samples
    __syncthreads();

    // fc2: 4 threads per output h, prefetched W2 slices
    {
        float dp = 0.f;
        #pragma unroll
        for (int j = 0; j < 6; ++j) {
            const float4 f = w2v[j];
            const int k = q * 24 + j * 4;
            dp = fmaf(f.x, xcat[k],     dp);
            dp = fmaf(f.y, xcat[k + 1], dp);
            dp = fmaf(f.z, xcat[k + 2], dp);
            dp = fmaf(f.w, xcat[k + 3], dp);
        }
        dp += __shfl_xor(dp, 1);
        dp += __shfl_xor(dp, 2);
        if (q == 0) h64[hh] = fmaxf(dp + b2v, 0.f);
    }
    __syncthreads();

    if (t < 64) {                  // parallel final dot (prefetched W3)
        float r = w3v * h64[t];
        #pragma unroll
        for (int d = 1; d < 64; d <<= 1) r += __shfl_xor(r, d);
        if (t == 0) out[0] = r + b3v;
    }
    if (t < 32) out[1 + t] = (t == amax) ? 1.f : 0.f;
}

extern "C" void kernel_launch(void* const* d_in, const int* in_sizes, int n_in,
                              void* d_out, int out_size, void* d_ws, size_t ws_size,
                              hipStream_t stream) {
    const float* inputs  = (const float*)d_in[0];
    const float* act_idx = (const float*)d_in[1];
    const float* other   = (const float*)d_in[2];
    const float* W11     = (const float*)d_in[3];
    const float* b11     = (const float*)d_in[4];
    const float* W12     = (const float*)d_in[5];
    const float* b12     = (const float*)d_in[6];
    const float* Wa      = (const float*)d_in[7];
    // d_in[8] = ba : unused (softmax shift-invariant)
    const float* Wao     = (const float*)d_in[9];
    const float* bao     = (const float*)d_in[10];
    const float* W2      = (const float*)d_in[11];
    const float* b2      = (const float*)d_in[12];
    const float* W3      = (const float*)d_in[13];
    const float* b3      = (const float*)d_in[14];
    float* ws = (float*)d_ws;

    // every ws slot k_final reads is written by k_part -> no memset needed
    k_part<<<GRID1, 1024, 0, stream>>>(other, W12, b12, Wa,
                                       inputs, act_idx, W11, b11, ws);
    k_final<<<1, 256, 0, stream>>>(ws, Wao, bao, W2, b2, W3, b3, (float*)d_out);
}